// Round 1
// 599.586 us; speedup vs baseline: 1.0289x; 1.0289x over previous
//
#include <hip/hip_runtime.h>
#include <cstdint>

#define ROW_N 8192
#define TPB   256
#define CAP   512

// Order-preserving float->uint32 transform: unsigned compare == float compare.
__device__ __forceinline__ unsigned int fkey(float p) {
  unsigned int b = __float_as_uint(p);
  return (b & 0x80000000u) ? ~b : (b | 0x80000000u);
}
__device__ __forceinline__ float fkey_inv(unsigned int t) {
  unsigned int b = (t & 0x80000000u) ? (t & 0x7fffffffu) : ~t;
  return __uint_as_float(b);
}

// Approximate screening key: key2 = perturbed * log2e, via 2 native v_log_f32.
// w = -ln(u+eps)+eps computed in log2 domain; monotone transform of the precise
// perturbed value. For w < 1e-5 (u extremely close to 1 -> huge gumbel, and the
// region where HW log2's abs error near 1.0 becomes a large *relative* error on
// w) we force candidacy with a saturated key; the precise recompute ranks them.
__device__ __forceinline__ unsigned int akey(float lg, float uu) {
  float l2u = __log2f(uu + 1e-8f);
  float w   = fmaf(l2u, -0.6931471805599453f, 1e-8f);
  float p2  = fmaf(lg, 1.4426950408889634f, -__log2f(w));
  p2 = (w < 1e-5f) ? 3.0e38f : p2;
  return fkey(p2);
}

__device__ __forceinline__ uint64_t shfl_xor_u64(uint64_t v, int m) {
  unsigned int lo = (unsigned int)v, hi = (unsigned int)(v >> 32);
  lo = __shfl_xor(lo, m, 64);
  hi = __shfl_xor(hi, m, 64);
  return ((uint64_t)hi << 32) | lo;
}
__device__ __forceinline__ uint64_t wave_max_u64(uint64_t v) {
#pragma unroll
  for (int s = 32; s >= 1; s >>= 1) {
    uint64_t o = shfl_xor_u64(v, s);
    v = (o > v) ? o : v;
  }
  return v;
}

struct alignas(16) u64x2 { uint64_t a, b; };

// __launch_bounds__(256, 4): cap VGPRs at 128 (4 waves/EU = 16 waves/CU).
// VGPR=88 previously forced the compiler to consume Phase-A loads in 2-3-deep
// batches (16 float4 payloads alone need 64 VGPRs) -> latency-serialized.
__global__ __launch_bounds__(TPB, 4) void gumbel_topk_kernel(
    const float* __restrict__ logits, const float* __restrict__ u,
    float* __restrict__ out) {
  const int row  = blockIdx.x;
  const int tid  = threadIdx.x;
  const int lane = tid & 63;
  const int wave = tid >> 6;

  __shared__ unsigned int s_cnt, s_t;
  __shared__ alignas(16) unsigned int s_gmax[64];     // group-of-4 thread maxes
  __shared__ unsigned int s_idx[CAP];                 // candidate element indices
  __shared__ alignas(16) uint64_t s_comp[CAP + 2];    // precise composite keys (+pad)
  __shared__ float        s_lg[CAP];                  // candidate original logits
  __shared__ float        s_red[8];                   // [0..3] wave maxes, [4..7] wave sums

  if (tid == 0) { s_cnt = 0; s_t = 0xFFFFFFFFu; }

  const float4* L4 = reinterpret_cast<const float4*>(logits) + (size_t)row * (ROW_N / 4);
  const float4* U4 = reinterpret_cast<const float4*>(u)      + (size_t)row * (ROW_N / 4);
  float4*       O4 = reinterpret_cast<float4*>(out)          + (size_t)row * (ROW_N / 4);

  // ---- Phase A-issue: all 16 loads up front, interleaved L/U pairs so pair j
  // becomes consumable after 2j+2 in-order vmcnt completions (progressive overlap).
  float4 lv[8], uv[8];
#pragma unroll
  for (int j = 0; j < 8; ++j) {
    lv[j] = L4[j * TPB + tid];
    uv[j] = U4[j * TPB + tid];
  }

  // ---- Zero-fill output row (stores issued AFTER the loads: vmcnt is an
  // in-order counter, so waits for load j never drain these stores; the
  // barriers before the final scatter order them).
  {
    float4 z = make_float4(0.f, 0.f, 0.f, 0.f);
#pragma unroll
    for (int j = 0; j < 8; ++j) O4[j * TPB + tid] = z;
  }

  // ---- Phase A-compute: approx keys, 32/thread (2 v_log + 3 fma each).
  unsigned int k[32];
  unsigned int M = 0;
#pragma unroll
  for (int j = 0; j < 8; ++j) {
    k[j * 4 + 0] = akey(lv[j].x, uv[j].x);
    k[j * 4 + 1] = akey(lv[j].y, uv[j].y);
    k[j * 4 + 2] = akey(lv[j].z, uv[j].z);
    k[j * 4 + 3] = akey(lv[j].w, uv[j].w);
    M = max(M, max(max(k[j * 4 + 0], k[j * 4 + 1]), max(k[j * 4 + 2], k[j * 4 + 3])));
  }

  // ---- Phase B: t = 32nd-largest of 64 group-of-4 maxes. Each group max IS a
  // distinct element, so the top-32 group maxes are 32 distinct elements with
  // key >= t  =>  t <= true 32nd-largest element key (screening stays valid).
  // O(TPB) LDS work instead of the old O(TPB^2/4) 256-entry all-thread scan.
  {
    unsigned int g = max(M, (unsigned int)__shfl_xor(M, 1, 64));
    g = max(g, (unsigned int)__shfl_xor(g, 2, 64));
    if ((tid & 3) == 0) s_gmax[tid >> 2] = g;
  }
  __syncthreads();
  if (tid < 64) {
    unsigned int mine = s_gmax[tid];
    unsigned int cnt = 0;
    const uint4* gm4 = reinterpret_cast<const uint4*>(s_gmax);
#pragma unroll
    for (int i = 0; i < 16; ++i) {
      uint4 v = gm4[i];
      cnt += (v.x > mine) + (v.y > mine) + (v.z > mine) + (v.w > mine);
    }
    if (cnt < 32) atomicMin(&s_t, mine);  // min over top-32 group maxes
  }
  __syncthreads();
  // Screening threshold with margin Delta = 0.25 log2-units (>= 2x approx error).
  const unsigned int tm = fkey(fkey_inv(s_t) - 0.25f);

  // ---- Phase C: collect candidate indices (approx key >= tm). Expected ~90/row.
#pragma unroll
  for (int j = 0; j < 8; ++j) {
#pragma unroll
    for (int c = 0; c < 4; ++c) {
      if (k[j * 4 + c] >= tm) {
        unsigned int slot = atomicAdd(&s_cnt, 1u);
        if (slot < CAP)
          s_idx[slot] = (unsigned int)(j * TPB + tid) * 4u + (unsigned int)c;
      }
    }
  }
  __syncthreads();
  unsigned int C = s_cnt;

  // ---- Fallback (adversarial ties only; never taken for iid data): exact
  // per-wave top-32 by approx composite -> union of 128 indices.
  if (C > CAP) {
#pragma unroll 1
    for (int it = 0; it < 32; ++it) {
      uint64_t lm = 0;
#pragma unroll
      for (int i = 0; i < 32; ++i) {
        unsigned int idx = (unsigned int)((i >> 2) * TPB + tid) * 4u + (unsigned int)(i & 3);
        uint64_t comp = ((uint64_t)k[i] << 13) | (uint64_t)(8191u - idx);
        if (k[i] != 0u && comp > lm) lm = comp;
      }
      uint64_t wm = wave_max_u64(lm);
      if (lm == wm) {
#pragma unroll
        for (int i = 0; i < 32; ++i) {
          unsigned int idx = (unsigned int)((i >> 2) * TPB + tid) * 4u + (unsigned int)(i & 3);
          uint64_t comp = ((uint64_t)k[i] << 13) | (uint64_t)(8191u - idx);
          if (comp == wm) k[i] = 0u;
        }
      }
      if (lane == 0) s_idx[wave * 32 + it] = 8191u - (unsigned int)(wm & 8191u);
    }
    __syncthreads();
    C = 128;
  }

  // ---- Phase D1: precise recompute for candidates only (~90/row). Rolled loop:
  // ONE textual copy of the precise ocml logf pair. Composite (key<<13)|(8191-idx)
  // is distinct per element; bigger = better, ties -> smaller index (top_k rule).
  const float* Lrow = logits + (size_t)row * ROW_N;
  const float* Urow = u      + (size_t)row * ROW_N;
#pragma unroll 1
  for (unsigned int vi = tid; vi < C; vi += TPB) {
    unsigned int idx = s_idx[vi];
    float lg = Lrow[idx];
    float uu = Urow[idx];
    float p  = lg - logf(-logf(uu + 1e-8f) + 1e-8f);
    s_comp[vi] = ((uint64_t)fkey(p) << 13) | (uint64_t)(8191u - idx);
    s_lg[vi]   = lg;
  }
  if (tid == 0) s_comp[C] = 0;  // pad so the paired D2 reads never see garbage
  __syncthreads();

  // ---- Phase D2: exact selection by rank-counting (rank < 32 <=> selected;
  // composites distinct => exactly 32 selected). Paired b128 broadcast reads.
  float m_local = -3.4e38f;
  unsigned int sel = 0;
  float lgs[2];
  unsigned int ids[2];
  const unsigned int CP = (C + 1u) >> 1;   // pairs (pad covers odd C)
#pragma unroll
  for (int s = 0; s < 2; ++s) {
    unsigned int vi = tid + s * TPB;
    lgs[s] = 0.f; ids[s] = 0;
    if (vi < C) {
      uint64_t mine = s_comp[vi];
      unsigned int cnt = 0;
      const u64x2* c2 = reinterpret_cast<const u64x2*>(s_comp);
#pragma unroll 1
      for (unsigned int i = 0; i < CP; ++i) {
        u64x2 v = c2[i];
        cnt += (v.a > mine) ? 1u : 0u;
        cnt += (v.b > mine) ? 1u : 0u;
      }
      if (cnt < 32) {
        sel |= (1u << s);
        lgs[s] = s_lg[vi];
        ids[s] = s_idx[vi];
        m_local = fmaxf(m_local, lgs[s]);
      }
    }
  }

  // Block-wide max of selected logits.
  float m = m_local;
#pragma unroll
  for (int s = 32; s >= 1; s >>= 1) m = fmaxf(m, __shfl_xor(m, s, 64));
  if (lane == 0) s_red[wave] = m;
  __syncthreads();
  m = fmaxf(fmaxf(s_red[0], s_red[1]), fmaxf(s_red[2], s_red[3]));

  float e0 = (sel & 1u) ? expf(lgs[0] - m) : 0.f;
  float e1 = (sel & 2u) ? expf(lgs[1] - m) : 0.f;
  float sum = e0 + e1;
#pragma unroll
  for (int s = 32; s >= 1; s >>= 1) sum += __shfl_xor(sum, s, 64);
  if (lane == 0) s_red[4 + wave] = sum;
  __syncthreads();
  sum = (s_red[4] + s_red[5]) + (s_red[6] + s_red[7]);

  // Scatter the 32 softmax weights (ordered after the zero-fill by the barriers).
  float* Orow = out + (size_t)row * ROW_N;
  if (sel & 1u) Orow[ids[0]] = e0 / sum;
  if (sel & 2u) Orow[ids[1]] = e1 / sum;
}

extern "C" void kernel_launch(void* const* d_in, const int* in_sizes, int n_in,
                              void* d_out, int out_size, void* d_ws, size_t ws_size,
                              hipStream_t stream) {
  const float* logits = (const float*)d_in[0];
  const float* u      = (const float*)d_in[1];
  float*       out    = (float*)d_out;
  int rows = in_sizes[0] / ROW_N;   // 8192
  gumbel_topk_kernel<<<dim3(rows), dim3(TPB), 0, stream>>>(logits, u, out);
}